// Round 4
// baseline (378.179 us; speedup 1.0000x reference)
//
#include <hip/hip_runtime.h>
#include <math.h>

// EdgeFeaturizer: per-row top-12 smallest of 8192x8192 fp32 + 50-bin RBF.
// d_out (float32): [8192*12*2] edge_index encoded as floats, then
// [8192*12*50] features.
//
// R9 = MARGINAL-BW PROBE round (R8 structure + one extra full-row nt read).
// Motivation: R5/R6/R8 (three different structures) all time 341+-2 us,
// but rocprof top-5 only ever shows the harness's 1-GiB poison fills
// (~162 us) -- edge_kernel's own duration/BW has never been observed.
// Window arithmetic leaves ~115 us unexplained. This round measures the
// kernel's true marginal HBM read rate via the slope d(window)/d(bytes):
// each block additionally nt-reads row (row+4096)&8191 (different CU's
// working set -> no L1 aliasing with the real read; dm is never
// L3-resident because the fill re-dirties L3 every replay), sunk into an
// asm volatile so it cannot be DCE'd. Output is unchanged.
// Pre-committed readout:
//   +~160 us -> kernel reads at ~1.6 TB/s (attack load path next);
//   +~43  us -> kernel at stream ceiling (restore R8, declare roofline);
//   between  -> partial headroom.
// launch_bounds (512,4) this round so probe regs can't spill (occupancy
// proven irrelevant by R6/R8 nulls).
//
// Key=(float_bits<<32)|idx == top_k's (dist asc, idx asc) order.
// Exact wave-0 fallback guarantees correctness for any input.

#define N_ATOMS 8192
#define K 12
#define NBINS 50
#define CAP 192          // total candidates/row: Binom(8192,0.01) mean 82
#define BLOCK 512
#define MAX_RADIUS 8.0f
#define CAND_T 0.01f

typedef float f4 __attribute__((ext_vector_type(4)));

__global__ __launch_bounds__(BLOCK, 4) void edge_kernel(const float* __restrict__ dm,
                                                        float* __restrict__ out) {
    const int tid = threadIdx.x;
    const int row = blockIdx.x;
    const float* rowp = dm + (size_t)row * N_ATOMS;
    const f4* row4 = (const f4*)rowp;
    // Probe row: same data volume, different row -> marginal HBM read.
    const f4* prow4 =
        (const f4*)(dm + (size_t)((row + 4096) & (N_ATOMS - 1)) * N_ATOMS);

    __shared__ unsigned long long s_keys[CAP];  // 1.5 KiB
    __shared__ int s_cnt;
    __shared__ int s_selidx[K];
    __shared__ float s_seldist[K];

    // Issue all loads first; they stay in flight across the init barrier.
    f4 v[4], p[4];
    #pragma unroll
    for (int i = 0; i < 4; ++i)
        v[i] = __builtin_nontemporal_load(&row4[tid + i * BLOCK]);
    #pragma unroll
    for (int i = 0; i < 4; ++i)
        p[i] = __builtin_nontemporal_load(&prow4[tid + i * BLOCK]);

    if (tid == 0) s_cnt = 0;
    __syncthreads();  // s_cnt init visible to all waves

    // ---- phase 1: filter + unordered LDS append ----
    #pragma unroll
    for (int i = 0; i < 4; ++i) {
        int bidx = (tid + i * BLOCK) * 4;
        #pragma unroll
        for (int c = 0; c < 4; ++c) {
            float d = v[i][c];
            if (d < CAND_T) {
                int pos = atomicAdd(&s_cnt, 1);
                if (pos < CAP)
                    s_keys[pos] =
                        ((unsigned long long)__float_as_uint(d) << 32) |
                        (unsigned int)(bidx + c);
            }
        }
    }

    // ---- probe sink: forces the 4 probe loads to complete, no output ----
    {
        float acc = 0.0f;
        #pragma unroll
        for (int i = 0; i < 4; ++i)
            acc += p[i][0] + p[i][1] + p[i][2] + p[i][3];
        asm volatile("" ::"v"(acc));
    }
    __syncthreads();

    const int total = s_cnt;

    if (total >= K && total <= CAP) {
        // ---- rank select: rank = #keys strictly smaller (keys unique) ----
        for (int j = tid; j < total; j += BLOCK) {
            unsigned long long kj = s_keys[j];
            int rank = 0;
            for (int m2 = 0; m2 < total; ++m2)       // broadcast reads
                rank += (s_keys[m2] < kj) ? 1 : 0;
            if (rank < K) {
                s_selidx[rank] = (int)(kj & 0xFFFFFFFFull);
                s_seldist[rank] =
                    __uint_as_float((unsigned int)(kj >> 32));
            }
        }
    } else if (tid < 64) {
        // ---- exact wave-0 fallback (never taken on this input) ----
        const int lane = tid;
        unsigned long long last = 0ull;
        for (int r = 0; r < K; ++r) {
            unsigned long long best = ~0ull;
            for (int i = 0; i < 32; ++i) {
                int v4i = lane + i * 64;
                f4 w = __builtin_nontemporal_load(&row4[v4i]);
                int bidx = v4i * 4;
                #pragma unroll
                for (int c = 0; c < 4; ++c) {
                    float d = w[c];
                    float md = (d <= MAX_RADIUS) ? d
                                                 : __uint_as_float(0x7F800000u);
                    unsigned long long key =
                        ((unsigned long long)__float_as_uint(md) << 32) |
                        (unsigned int)(bidx + c);
                    if (((r == 0) || (key > last)) && key < best) best = key;
                }
            }
            #pragma unroll
            for (int off = 32; off > 0; off >>= 1) {
                unsigned long long other = __shfl_xor(best, off, 64);
                if (other < best) best = other;
            }
            if (lane == 0) {
                int idx = (int)(best & 0xFFFFFFFFull);
                s_selidx[r] = idx;
                s_seldist[r] = rowp[idx];  // original dm value
            }
            last = best;
        }
    }
    __syncthreads();  // selection visible to all waves

    // ---- outputs (non-temporal: never re-read) ----
    float* out_ei = out;
    float* out_ef = out + (size_t)N_ATOMS * K * 2;
    if (tid < 2 * K) {
        int r = tid >> 1, comp = tid & 1;
        __builtin_nontemporal_store(
            comp ? (float)s_selidx[r] : (float)row,
            &out_ei[((size_t)row * K + r) * 2 + comp]);
    }
    for (int t = tid; t < K * NBINS; t += BLOCK) {
        int r = t / NBINS, b = t - r * NBINS;
        float d = s_seldist[r];
        float z = (d - (float)b * (1.0f / 49.0f)) * 5.0f;
        __builtin_nontemporal_store(__expf(-0.5f * z * z),
                                    &out_ef[(size_t)row * K * NBINS + t]);
    }
}

extern "C" void kernel_launch(void* const* d_in, const int* in_sizes, int n_in,
                              void* d_out, int out_size, void* d_ws, size_t ws_size,
                              hipStream_t stream) {
    const float* dm = (const float*)d_in[0];
    float* out = (float*)d_out;
    edge_kernel<<<N_ATOMS, BLOCK, 0, stream>>>(dm, out);
}

// Round 5
// 339.803 us; speedup vs baseline: 1.1129x; 1.1129x over previous
//
#include <hip/hip_runtime.h>
#include <math.h>

// EdgeFeaturizer: per-row top-12 smallest of 8192x8192 fp32 + 50-bin RBF.
// d_out (float32): [8192*12*2] edge_index encoded as floats, then
// [8192*12*50] features.
//
// R10 = R8 RESTORED (best known: 340.6 us). R9's marginal-BW probe
// (extra full-row nt read per block, +268 MB) cost +37.6 us -> marginal
// kernel read rate ~7.1 TB/s, i.e. the scan is AT the HBM stream
// ceiling. Window decomposition: ~162 us harness poison fill + ~45 us
// kernel (268 MB read + 20 MB write at ceiling) + ~130 us harness reset
// dispatches -- kernel-side work is roofline-bound; the rest is not
// addressable from kernel source. R5/R6/R8 (three structures) all timed
// 341+-2 us because all were read-stream-bound at the same ceiling.
//
// Carried design:
// - nt loads: the 1 GiB poison fill re-dirties L3 every replay, so dm can
//   never be L3-resident; allocating loads cost +23 us (R7) via forced
//   dirty evictions. nt stores for outputs (never re-read).
// - block-per-row (512 thr), unordered LDS atomicAdd append (~82/row;
//   rank-select is order-independent), rank select over <=CAP keys.
// - Key=(float_bits<<32)|idx == top_k's (dist asc, idx asc) order.
// - Exact wave-0 fallback guarantees correctness for any input.

#define N_ATOMS 8192
#define K 12
#define NBINS 50
#define CAP 192          // total candidates/row: Binom(8192,0.01) mean 82
#define BLOCK 512
#define MAX_RADIUS 8.0f
#define CAND_T 0.01f

typedef float f4 __attribute__((ext_vector_type(4)));

__global__ __launch_bounds__(BLOCK, 8) void edge_kernel(const float* __restrict__ dm,
                                                        float* __restrict__ out) {
    const int tid = threadIdx.x;
    const int row = blockIdx.x;
    const float* rowp = dm + (size_t)row * N_ATOMS;
    const f4* row4 = (const f4*)rowp;

    __shared__ unsigned long long s_keys[CAP];  // 1.5 KiB
    __shared__ int s_cnt;
    __shared__ int s_selidx[K];
    __shared__ float s_seldist[K];

    // Issue all loads first; they stay in flight across the init barrier.
    f4 v[4];
    #pragma unroll
    for (int i = 0; i < 4; ++i)
        v[i] = __builtin_nontemporal_load(&row4[tid + i * BLOCK]);

    if (tid == 0) s_cnt = 0;
    __syncthreads();  // s_cnt init visible to all waves

    // ---- phase 1: filter + unordered LDS append ----
    #pragma unroll
    for (int i = 0; i < 4; ++i) {
        int bidx = (tid + i * BLOCK) * 4;
        #pragma unroll
        for (int c = 0; c < 4; ++c) {
            float d = v[i][c];
            if (d < CAND_T) {
                int pos = atomicAdd(&s_cnt, 1);
                if (pos < CAP)
                    s_keys[pos] =
                        ((unsigned long long)__float_as_uint(d) << 32) |
                        (unsigned int)(bidx + c);
            }
        }
    }
    __syncthreads();

    const int total = s_cnt;

    if (total >= K && total <= CAP) {
        // ---- rank select: rank = #keys strictly smaller (keys unique) ----
        for (int j = tid; j < total; j += BLOCK) {
            unsigned long long kj = s_keys[j];
            int rank = 0;
            for (int m2 = 0; m2 < total; ++m2)       // broadcast reads
                rank += (s_keys[m2] < kj) ? 1 : 0;
            if (rank < K) {
                s_selidx[rank] = (int)(kj & 0xFFFFFFFFull);
                s_seldist[rank] =
                    __uint_as_float((unsigned int)(kj >> 32));
            }
        }
    } else if (tid < 64) {
        // ---- exact wave-0 fallback (never taken on this input) ----
        const int lane = tid;
        unsigned long long last = 0ull;
        for (int r = 0; r < K; ++r) {
            unsigned long long best = ~0ull;
            for (int i = 0; i < 32; ++i) {
                int v4i = lane + i * 64;
                f4 w = __builtin_nontemporal_load(&row4[v4i]);
                int bidx = v4i * 4;
                #pragma unroll
                for (int c = 0; c < 4; ++c) {
                    float d = w[c];
                    float md = (d <= MAX_RADIUS) ? d
                                                 : __uint_as_float(0x7F800000u);
                    unsigned long long key =
                        ((unsigned long long)__float_as_uint(md) << 32) |
                        (unsigned int)(bidx + c);
                    if (((r == 0) || (key > last)) && key < best) best = key;
                }
            }
            #pragma unroll
            for (int off = 32; off > 0; off >>= 1) {
                unsigned long long other = __shfl_xor(best, off, 64);
                if (other < best) best = other;
            }
            if (lane == 0) {
                int idx = (int)(best & 0xFFFFFFFFull);
                s_selidx[r] = idx;
                s_seldist[r] = rowp[idx];  // original dm value
            }
            last = best;
        }
    }
    __syncthreads();  // selection visible to all waves

    // ---- outputs (non-temporal: never re-read) ----
    float* out_ei = out;
    float* out_ef = out + (size_t)N_ATOMS * K * 2;
    if (tid < 2 * K) {
        int r = tid >> 1, comp = tid & 1;
        __builtin_nontemporal_store(
            comp ? (float)s_selidx[r] : (float)row,
            &out_ei[((size_t)row * K + r) * 2 + comp]);
    }
    for (int t = tid; t < K * NBINS; t += BLOCK) {
        int r = t / NBINS, b = t - r * NBINS;
        float d = s_seldist[r];
        float z = (d - (float)b * (1.0f / 49.0f)) * 5.0f;
        __builtin_nontemporal_store(__expf(-0.5f * z * z),
                                    &out_ef[(size_t)row * K * NBINS + t]);
    }
}

extern "C" void kernel_launch(void* const* d_in, const int* in_sizes, int n_in,
                              void* d_out, int out_size, void* d_ws, size_t ws_size,
                              hipStream_t stream) {
    const float* dm = (const float*)d_in[0];
    float* out = (float*)d_out;
    edge_kernel<<<N_ATOMS, BLOCK, 0, stream>>>(dm, out);
}